// Round 2
// baseline (938.772 us; speedup 1.0000x reference)
//
#include <hip/hip_runtime.h>

#define BATCH 4
#define H 720
#define W 1280
#define HW (H*W)

typedef _Float16 f16x8 __attribute__((ext_vector_type(8)));
typedef __attribute__((ext_vector_type(4))) float f32x4;

// weight pack byte offsets within WP region (each frag = 64 lanes * 16 B = 1 KB)
#define WP1_B 0        // 6 frags  = 6144 B
#define WP2_B 8192     // 27 frags = 27648 B
#define WP3A_B 40960   // 18 frags = 18432 B
#define WP3B_B 61440   // 18 frags = 18432 B
#define WP4_B 81920    // 9 frags  = 9216 B
#define WP_BYTES 98304

__device__ __forceinline__ ushort f2h(float x) {
    union { _Float16 h; ushort u; } c; c.h = (_Float16)x; return c.u;
}

// ---------------- pack input band: NCHW fp32 x2 -> NHWC8 f16 ----------------
// X buffer rows cover image rows [xbase, xbase+RBX); only [xr0, xr0+rows_x) written.
__global__ void pack_x_kernel(const float* __restrict__ f1, const float* __restrict__ f3,
                              ushort* __restrict__ X,
                              int xr0, int rows_x, int xbase, int RBX) {
    int p = blockIdx.x * 256 + threadIdx.x;
    int npix = BATCH * rows_x * W;
    if (p >= npix) return;
    int b = p / (rows_x * W);
    int rem = p - b * (rows_x * W);
    int ri = rem / W;
    int col = rem - ri * W;
    int img_row = xr0 + ri;
    int buf_row = img_row - xbase;
    const float* p1 = f1 + (size_t)b * 3 * HW + (size_t)img_row * W + col;
    const float* p3 = f3 + (size_t)b * 3 * HW + (size_t)img_row * W + col;
    union { ushort u[8]; uint4 v; } r;
    r.u[0] = f2h(p1[0]);  r.u[1] = f2h(p1[HW]);  r.u[2] = f2h(p1[2*HW]);
    r.u[3] = f2h(p3[0]);  r.u[4] = f2h(p3[HW]);  r.u[5] = f2h(p3[2*HW]);
    r.u[6] = 0; r.u[7] = 0;
    *reinterpret_cast<uint4*>(X + (((size_t)b * RBX + buf_row) * W + col) * 8) = r.v;
}

// ---------------- pack weights into A-fragment order (f16) ----------------
// A-frag (16x16x32): lane l supplies A[m][k], m = l&15, k = 8*(l>>4)+j, j=0..7
__global__ void pack_w_kernel(const float* __restrict__ w1, const float* __restrict__ w2,
                              const float* __restrict__ w3, const float* __restrict__ w4,
                              ushort* __restrict__ wp1, ushort* __restrict__ wp2,
                              ushort* __restrict__ wp3a, ushort* __restrict__ wp3b,
                              ushort* __restrict__ wp4) {
    int i = blockIdx.x * 256 + threadIdx.x;
    if (i < 3072) {
        // wp1: frag f = dy*2+mt ; k -> (dx = k>>3, ci = k&7)
        int j = i & 7, l = (i >> 3) & 63, f = i >> 9;
        int dy = f >> 1, mt = f & 1;
        int dx = l >> 4, ci = j, och = mt * 16 + (l & 15);
        float v = 0.f;
        if (dx < 3 && ci < 6) v = w1[((och * 6 + ci) * 3 + dy) * 3 + dx];
        wp1[i] = f2h(v);
        return;
    }
    i -= 3072;
    if (i < 13824) {
        int j = i & 7, l = (i >> 3) & 63, f = i >> 9;
        int tap = f / 3, mt = f - tap * 3;
        int dy = tap / 3, dx = tap - dy * 3;
        int och = mt * 16 + (l & 15), ci = (l >> 4) * 8 + j;
        wp2[i] = f2h(w2[((och * 32 + ci) * 3 + dy) * 3 + dx]);
        return;
    }
    i -= 13824;
    if (i < 9216) {
        int j = i & 7, l = (i >> 3) & 63, f = i >> 9;
        int tap = f >> 1, mt = f & 1;
        int dy = tap / 3, dx = tap - dy * 3;
        int och = mt * 16 + (l & 15), ci = (l >> 4) * 8 + j;
        wp3a[i] = f2h(w3[((och * 48 + ci) * 3 + dy) * 3 + dx]);
        return;
    }
    i -= 9216;
    if (i < 9216) {
        int j = i & 7, l = (i >> 3) & 63, f = i >> 9;
        int tap = f >> 1, mt = f & 1;
        int dy = tap / 3, dx = tap - dy * 3;
        int och = mt * 16 + (l & 15), ci = 32 + (l >> 4) * 8 + j;
        float v = 0.f;
        if (ci < 48) v = w3[((och * 48 + ci) * 3 + dy) * 3 + dx];
        wp3b[i] = f2h(v);
        return;
    }
    i -= 9216;
    if (i < 4608) {
        int j = i & 7, l = (i >> 3) & 63, tap = i >> 9;
        int dy = tap / 3, dx = tap - dy * 3;
        int och = l & 15, ci = (l >> 4) * 8 + j;
        float v = 0.f;
        if (och < 3) v = w4[((och * 32 + ci) * 3 + dy) * 3 + dx];
        wp4[i] = f2h(v);
    }
}

__device__ __forceinline__ void lds_copy(const unsigned char* __restrict__ g, char* s, int bytes) {
    const uint4* gs = reinterpret_cast<const uint4*>(g);
    uint4* ss = reinterpret_cast<uint4*>(s);
    for (int i = threadIdx.x; i < bytes / 16; i += 256) ss[i] = gs[i];
    __syncthreads();
}

// ---------------- conv1: X(8ch) -> Y1(32ch), relu ----------------
__global__ __launch_bounds__(256) void conv1_kernel(const ushort* __restrict__ Xg,
                                                    const float* __restrict__ bias,
                                                    ushort* __restrict__ Y,
                                                    const unsigned char* __restrict__ wp,
                                                    int y0, int xbase, int RBX, int y1base, int RBY1) {
    __shared__ char lds[6144];
    lds_copy(wp, lds, 6144);
    int wave = threadIdx.x >> 6, lane = threadIdx.x & 63;
    int l15 = lane & 15, lhi = lane >> 4;
    int y = y0 + blockIdx.y, b = blockIdx.z;
    int x0 = blockIdx.x * 256 + wave * 64;

    f32x4 acc[2][4] = {};
    #pragma unroll
    for (int dy = 0; dy < 3; ++dy) {
        int yy = y + dy - 1;
        bool rv = (yy >= 0 && yy < H);
        size_t srow = ((size_t)b * RBX + (yy - xbase)) * W;
        f16x8 bfrag[4];
        #pragma unroll
        for (int nt = 0; nt < 4; ++nt) {
            int xc = x0 + nt * 16 + l15 + lhi - 1;   // dx folded into k: dx = lhi
            uint4 v = make_uint4(0, 0, 0, 0);
            if (rv && lhi < 3 && xc >= 0 && xc < W)
                v = *reinterpret_cast<const uint4*>(Xg + (srow + xc) * 8);
            bfrag[nt] = *reinterpret_cast<f16x8*>(&v);
        }
        #pragma unroll
        for (int mt = 0; mt < 2; ++mt) {
            f16x8 a = *reinterpret_cast<f16x8*>(lds + ((dy * 2 + mt) * 64 + lane) * 16);
            #pragma unroll
            for (int nt = 0; nt < 4; ++nt)
                acc[mt][nt] = __builtin_amdgcn_mfma_f32_16x16x32_f16(a, bfrag[nt], acc[mt][nt], 0, 0, 0);
        }
    }
    size_t drow = ((size_t)b * RBY1 + (y - y1base)) * W;
    #pragma unroll
    for (int mt = 0; mt < 2; ++mt) {
        float4 bs = *reinterpret_cast<const float4*>(bias + mt * 16 + lhi * 4);
        const float* bsp = reinterpret_cast<const float*>(&bs);
        #pragma unroll
        for (int nt = 0; nt < 4; ++nt) {
            size_t pix = drow + x0 + nt * 16 + l15;
            ushort o[4];
            #pragma unroll
            for (int r = 0; r < 4; ++r) o[r] = f2h(fmaxf(acc[mt][nt][r] + bsp[r], 0.f));
            *reinterpret_cast<uint2*>(Y + pix * 32 + mt * 16 + lhi * 4) = *reinterpret_cast<uint2*>(o);
        }
    }
}

// ---------------- conv2: Y1(32ch) -> Y2(48ch), relu ----------------
__global__ __launch_bounds__(256) void conv2_kernel(const ushort* __restrict__ Y1,
                                                    const float* __restrict__ bias,
                                                    ushort* __restrict__ Y2,
                                                    const unsigned char* __restrict__ wp,
                                                    int y0, int y1base, int RBY1, int y2base, int RBY2) {
    __shared__ char lds[27648];
    lds_copy(wp, lds, 27648);
    int wave = threadIdx.x >> 6, lane = threadIdx.x & 63;
    int l15 = lane & 15, lhi = lane >> 4;
    int y = y0 + blockIdx.y, b = blockIdx.z;
    int x0 = blockIdx.x * 256 + wave * 64;

    f32x4 acc[3][4] = {};
    #pragma unroll
    for (int dy = 0; dy < 3; ++dy) {
        int yy = y + dy - 1;
        bool rv = (yy >= 0 && yy < H);
        size_t srow = ((size_t)b * RBY1 + (yy - y1base)) * W;
        #pragma unroll
        for (int dx = 0; dx < 3; ++dx) {
            int tap = dy * 3 + dx;
            f16x8 bfrag[4];
            #pragma unroll
            for (int nt = 0; nt < 4; ++nt) {
                int xc = x0 + nt * 16 + l15 + dx - 1;
                uint4 v = make_uint4(0, 0, 0, 0);
                if (rv && xc >= 0 && xc < W)
                    v = *reinterpret_cast<const uint4*>(Y1 + (srow + xc) * 32 + lhi * 8);
                bfrag[nt] = *reinterpret_cast<f16x8*>(&v);
            }
            #pragma unroll
            for (int mt = 0; mt < 3; ++mt) {
                f16x8 a = *reinterpret_cast<f16x8*>(lds + ((tap * 3 + mt) * 64 + lane) * 16);
                #pragma unroll
                for (int nt = 0; nt < 4; ++nt)
                    acc[mt][nt] = __builtin_amdgcn_mfma_f32_16x16x32_f16(a, bfrag[nt], acc[mt][nt], 0, 0, 0);
            }
        }
    }
    size_t drow = ((size_t)b * RBY2 + (y - y2base)) * W;
    #pragma unroll
    for (int mt = 0; mt < 3; ++mt) {
        float4 bs = *reinterpret_cast<const float4*>(bias + mt * 16 + lhi * 4);
        const float* bsp = reinterpret_cast<const float*>(&bs);
        #pragma unroll
        for (int nt = 0; nt < 4; ++nt) {
            size_t pix = drow + x0 + nt * 16 + l15;
            ushort o[4];
            #pragma unroll
            for (int r = 0; r < 4; ++r) o[r] = f2h(fmaxf(acc[mt][nt][r] + bsp[r], 0.f));
            *reinterpret_cast<uint2*>(Y2 + pix * 48 + mt * 16 + lhi * 4) = *reinterpret_cast<uint2*>(o);
        }
    }
}

// ---------------- conv3: Y2(48ch) -> Y3(32ch), relu ----------------
__global__ __launch_bounds__(256) void conv3_kernel(const ushort* __restrict__ Y2,
                                                    const float* __restrict__ bias,
                                                    ushort* __restrict__ Y3,
                                                    const unsigned char* __restrict__ wpa,
                                                    const unsigned char* __restrict__ wpb,
                                                    int y0, int y2base, int RBY2, int y3base, int RBY3) {
    __shared__ char lds[36864];
    {
        const uint4* ga = reinterpret_cast<const uint4*>(wpa);
        const uint4* gb = reinterpret_cast<const uint4*>(wpb);
        uint4* ss = reinterpret_cast<uint4*>(lds);
        for (int i = threadIdx.x; i < 18432 / 16; i += 256) { ss[i] = ga[i]; ss[i + 1152] = gb[i]; }
        __syncthreads();
    }
    int wave = threadIdx.x >> 6, lane = threadIdx.x & 63;
    int l15 = lane & 15, lhi = lane >> 4;
    int y = y0 + blockIdx.y, b = blockIdx.z;
    int x0 = blockIdx.x * 256 + wave * 64;

    f32x4 acc[2][4] = {};
    #pragma unroll
    for (int dy = 0; dy < 3; ++dy) {
        int yy = y + dy - 1;
        bool rv = (yy >= 0 && yy < H);
        size_t srow = ((size_t)b * RBY2 + (yy - y2base)) * W;
        #pragma unroll
        for (int dx = 0; dx < 3; ++dx) {
            int tap = dy * 3 + dx;
            f16x8 b0[4], b1[4];
            #pragma unroll
            for (int nt = 0; nt < 4; ++nt) {
                int xc = x0 + nt * 16 + l15 + dx - 1;
                bool valid = rv && xc >= 0 && xc < W;
                uint4 v0 = make_uint4(0, 0, 0, 0), v1 = make_uint4(0, 0, 0, 0);
                if (valid)
                    v0 = *reinterpret_cast<const uint4*>(Y2 + (srow + xc) * 48 + lhi * 8);
                if (valid && lhi < 2)
                    v1 = *reinterpret_cast<const uint4*>(Y2 + (srow + xc) * 48 + 32 + lhi * 8);
                b0[nt] = *reinterpret_cast<f16x8*>(&v0);
                b1[nt] = *reinterpret_cast<f16x8*>(&v1);
            }
            #pragma unroll
            for (int mt = 0; mt < 2; ++mt) {
                f16x8 a0 = *reinterpret_cast<f16x8*>(lds + ((tap * 2 + mt) * 64 + lane) * 16);
                f16x8 a1 = *reinterpret_cast<f16x8*>(lds + 18432 + ((tap * 2 + mt) * 64 + lane) * 16);
                #pragma unroll
                for (int nt = 0; nt < 4; ++nt) {
                    acc[mt][nt] = __builtin_amdgcn_mfma_f32_16x16x32_f16(a0, b0[nt], acc[mt][nt], 0, 0, 0);
                    acc[mt][nt] = __builtin_amdgcn_mfma_f32_16x16x32_f16(a1, b1[nt], acc[mt][nt], 0, 0, 0);
                }
            }
        }
    }
    size_t drow = ((size_t)b * RBY3 + (y - y3base)) * W;
    #pragma unroll
    for (int mt = 0; mt < 2; ++mt) {
        float4 bs = *reinterpret_cast<const float4*>(bias + mt * 16 + lhi * 4);
        const float* bsp = reinterpret_cast<const float*>(&bs);
        #pragma unroll
        for (int nt = 0; nt < 4; ++nt) {
            size_t pix = drow + x0 + nt * 16 + l15;
            ushort o[4];
            #pragma unroll
            for (int r = 0; r < 4; ++r) o[r] = f2h(fmaxf(acc[mt][nt][r] + bsp[r], 0.f));
            *reinterpret_cast<uint2*>(Y3 + pix * 32 + mt * 16 + lhi * 4) = *reinterpret_cast<uint2*>(o);
        }
    }
}

__device__ __forceinline__ float edgef(float t) {
    float a = 1.f / (1.f + expf(-(t - 0.1f) * 10.f));
    float c = 1.f / (1.f + expf(-(0.9f - t) * 10.f));
    return fminf(a, c);
}

// ---------------- conv4 + mask/avg/clip epilogue -> out NCHW fp32 ----------------
__global__ __launch_bounds__(256) void conv4_kernel(const ushort* __restrict__ Y3,
                                                    const float* __restrict__ b4,
                                                    const float* __restrict__ f1,
                                                    const float* __restrict__ f3,
                                                    float* __restrict__ out,
                                                    const unsigned char* __restrict__ wp,
                                                    int y0, int y3base, int RBY3) {
    __shared__ char lds[9216];
    lds_copy(wp, lds, 9216);
    int wave = threadIdx.x >> 6, lane = threadIdx.x & 63;
    int l15 = lane & 15, lhi = lane >> 4;
    int y = y0 + blockIdx.y, b = blockIdx.z;
    int x0 = blockIdx.x * 256 + wave * 64;

    f32x4 acc[4] = {};
    #pragma unroll
    for (int dy = 0; dy < 3; ++dy) {
        int yy = y + dy - 1;
        bool rv = (yy >= 0 && yy < H);
        size_t srow = ((size_t)b * RBY3 + (yy - y3base)) * W;
        #pragma unroll
        for (int dx = 0; dx < 3; ++dx) {
            int tap = dy * 3 + dx;
            f16x8 bfrag[4];
            #pragma unroll
            for (int nt = 0; nt < 4; ++nt) {
                int xc = x0 + nt * 16 + l15 + dx - 1;
                uint4 v = make_uint4(0, 0, 0, 0);
                if (rv && xc >= 0 && xc < W)
                    v = *reinterpret_cast<const uint4*>(Y3 + (srow + xc) * 32 + lhi * 8);
                bfrag[nt] = *reinterpret_cast<f16x8*>(&v);
            }
            f16x8 a = *reinterpret_cast<f16x8*>(lds + (tap * 64 + lane) * 16);
            #pragma unroll
            for (int nt = 0; nt < 4; ++nt)
                acc[nt] = __builtin_amdgcn_mfma_f32_16x16x32_f16(a, bfrag[nt], acc[nt], 0, 0, 0);
        }
    }
    if (lhi == 0) {   // och = reg index r (0..2) at pixel col l15
        float bv0 = b4[0], bv1 = b4[1], bv2 = b4[2];
        float ty = (float)y * (1.f / (H - 1));
        float ey = edgef(ty);
        #pragma unroll
        for (int nt = 0; nt < 4; ++nt) {
            int x = x0 + nt * 16 + l15;
            float tx = (float)x * (1.f / (W - 1));
            float m = edgef(tx) * ey;
            float om = 1.f - m;
            #pragma unroll
            for (int r = 0; r < 3; ++r) {
                float bv = (r == 0) ? bv0 : (r == 1 ? bv1 : bv2);
                size_t idx = ((size_t)(b * 3 + r) * H + y) * W + x;
                float avg = 0.5f * (f1[idx] + f3[idx]);
                float v = avg * om + (acc[nt][r] + bv) * m;
                out[idx] = fminf(fmaxf(v, -1.f), 1.f);
            }
        }
    }
}

extern "C" void kernel_launch(void* const* d_in, const int* in_sizes, int n_in,
                              void* d_out, int out_size, void* d_ws, size_t ws_size,
                              hipStream_t stream) {
    const float* f1 = (const float*)d_in[0];
    const float* f3 = (const float*)d_in[1];
    const float* w1 = (const float*)d_in[2];
    const float* b1 = (const float*)d_in[3];
    const float* w2 = (const float*)d_in[4];
    const float* b2 = (const float*)d_in[5];
    const float* w3 = (const float*)d_in[6];
    const float* b3 = (const float*)d_in[7];
    const float* w4 = (const float*)d_in[8];
    const float* b4 = (const float*)d_in[9];
    float* out = (float*)d_out;

    // ---- adaptive band sizing: fit per-band buffers + 128KB pack reserve in ws ----
    long avail = (long)ws_size - 131072;
    int RB = -1;
    for (int nb = 1; nb <= 180; ++nb) {
        int rb = (H + nb - 1) / nb;
        long need = 10240L * (120L * rb + 512);   // X(8ch,+8r) Y1(32,+6) Y2(48,+4) Y3(32,+2), f16, W=1280, B=4
        if (need <= avail) { RB = rb; break; }
    }
    if (RB < 0) return;   // workspace too small; fail validation without faulting

    int RBX = RB + 8, RBY1 = RB + 6, RBY2 = RB + 4, RBY3 = RB + 2;
    char* ws = (char*)d_ws;
    size_t offX  = 0;
    size_t offY1 = offX  + (size_t)BATCH * RBX  * W * 8  * 2;
    size_t offY2 = offY1 + (size_t)BATCH * RBY1 * W * 32 * 2;
    size_t offY3 = offY2 + (size_t)BATCH * RBY2 * W * 48 * 2;
    size_t offWP = offY3 + (size_t)BATCH * RBY3 * W * 32 * 2;
    ushort* X  = (ushort*)(ws + offX);
    ushort* Y1 = (ushort*)(ws + offY1);
    ushort* Y2 = (ushort*)(ws + offY2);
    ushort* Y3 = (ushort*)(ws + offY3);
    ushort* wp1  = (ushort*)(ws + offWP + WP1_B);
    ushort* wp2  = (ushort*)(ws + offWP + WP2_B);
    ushort* wp3a = (ushort*)(ws + offWP + WP3A_B);
    ushort* wp3b = (ushort*)(ws + offWP + WP3B_B);
    ushort* wp4  = (ushort*)(ws + offWP + WP4_B);

    pack_w_kernel<<<156, 256, 0, stream>>>(w1, w2, w3, w4, wp1, wp2, wp3a, wp3b, wp4);

    for (int r0 = 0; r0 < H; r0 += RB) {
        int r1 = r0 + RB; if (r1 > H) r1 = H;
        int xbase = r0 - 4, y1base = r0 - 3, y2base = r0 - 2, y3base = r0 - 1;

        int xr0 = r0 - 4 < 0 ? 0 : r0 - 4;
        int xr1 = r1 + 4 > H ? H : r1 + 4;
        int rows_x = xr1 - xr0;
        int npix = BATCH * rows_x * W;
        pack_x_kernel<<<(npix + 255) / 256, 256, 0, stream>>>(f1, f3, X, xr0, rows_x, xbase, RBX);

        int y10 = r0 - 3 < 0 ? 0 : r0 - 3;
        int y11 = r1 + 3 > H ? H : r1 + 3;
        conv1_kernel<<<dim3(W / 256, y11 - y10, BATCH), 256, 0, stream>>>(
            X, b1, Y1, (const unsigned char*)wp1, y10, xbase, RBX, y1base, RBY1);

        int y20 = r0 - 2 < 0 ? 0 : r0 - 2;
        int y21 = r1 + 2 > H ? H : r1 + 2;
        conv2_kernel<<<dim3(W / 256, y21 - y20, BATCH), 256, 0, stream>>>(
            Y1, b2, Y2, (const unsigned char*)wp2, y20, y1base, RBY1, y2base, RBY2);

        int y30 = r0 - 1 < 0 ? 0 : r0 - 1;
        int y31 = r1 + 1 > H ? H : r1 + 1;
        conv3_kernel<<<dim3(W / 256, y31 - y30, BATCH), 256, 0, stream>>>(
            Y2, b3, Y3, (const unsigned char*)wp3a, (const unsigned char*)wp3b,
            y30, y2base, RBY2, y3base, RBY3);

        conv4_kernel<<<dim3(W / 256, r1 - r0, BATCH), 256, 0, stream>>>(
            Y3, b4, f1, f3, out, (const unsigned char*)wp4, r0, y3base, RBY3);
    }
}

// Round 3
// 910.515 us; speedup vs baseline: 1.0310x; 1.0310x over previous
//
#include <hip/hip_runtime.h>

#define BATCH 4
#define H 720
#define W 1280
#define HW (H*W)
#define WX (W+4)      // X padded width  (cols: 0 pad | 1..W image | W+1..W+3 pad)
#define WP (W+2)      // Y1/Y2/Y3 padded width (cols: 0 pad | 1..W | W+1 pad)

typedef _Float16 f16x8 __attribute__((ext_vector_type(8)));
typedef __attribute__((ext_vector_type(4))) float f32x4;

// weight pack byte offsets within WP region (each frag = 64 lanes * 16 B = 1 KB)
#define WP1_B 0        // 6 frags  = 6144 B
#define WP2_B 8192     // 27 frags = 27648 B
#define WP3_B 40960    // 36 frags = 36864 B (a: 18 frags, b: 18 frags, contiguous)
#define WP4_B 81920    // 9 frags  = 9216 B
#define WP_BYTES 98304

__device__ __forceinline__ ushort f2h(float x) {
    union { _Float16 h; ushort u; } c; c.h = (_Float16)x; return c.u;
}

// Bijective chunked XCD swizzle: launched id -> work id so that ids on the same
// XCD (id%8) form a contiguous work chunk (row locality in L2).
__device__ __forceinline__ int xcd_work(int id, int nwg) {
    int q = nwg >> 3, r = nwg & 7;
    int k = id & 7, i = id >> 3;
    int extra = k < r ? k : r;
    return k * q + extra + i;
}

// ---------------- zero the column pads of all band buffers ----------------
__global__ void zero_pads_kernel(ushort* __restrict__ X, ushort* __restrict__ Y1,
                                 ushort* __restrict__ Y2, ushort* __restrict__ Y3,
                                 int RBX, int RBY1, int RBY2, int RBY3) {
    int i = blockIdx.x * 256 + threadIdx.x;
    uint4 z = make_uint4(0, 0, 0, 0);
    int nX = BATCH * RBX * 4;
    if (i < nX) {
        int c4 = i & 3, row = i >> 2;
        int col = (c4 == 0) ? 0 : (W + c4);       // 0, W+1, W+2, W+3
        *reinterpret_cast<uint4*>(X + ((size_t)row * WX + col) * 8) = z;
        return;
    }
    i -= nX;
    int n1 = BATCH * RBY1 * 2;
    if (i < n1) {
        int c = i & 1, row = i >> 1;
        int col = c ? (W + 1) : 0;
        uint4* p = reinterpret_cast<uint4*>(Y1 + ((size_t)row * WP + col) * 32);
        p[0] = z; p[1] = z; p[2] = z; p[3] = z;
        return;
    }
    i -= n1;
    int n2 = BATCH * RBY2 * 2;
    if (i < n2) {
        int c = i & 1, row = i >> 1;
        int col = c ? (W + 1) : 0;
        uint4* p = reinterpret_cast<uint4*>(Y2 + ((size_t)row * WP + col) * 48);
        p[0] = z; p[1] = z; p[2] = z; p[3] = z; p[4] = z; p[5] = z;
        return;
    }
    i -= n2;
    int n3 = BATCH * RBY3 * 2;
    if (i < n3) {
        int c = i & 1, row = i >> 1;
        int col = c ? (W + 1) : 0;
        uint4* p = reinterpret_cast<uint4*>(Y3 + ((size_t)row * WP + col) * 32);
        p[0] = z; p[1] = z; p[2] = z; p[3] = z;
    }
}

// ---------------- pack input band: NCHW fp32 x2 -> padded NHWC8 f16 ----------------
// Covers ALL RBX buffer rows; rows outside [0,H) are written as zeros.
__global__ void pack_x_kernel(const float* __restrict__ f1, const float* __restrict__ f3,
                              ushort* __restrict__ X, int xbase, int RBX) {
    int p = blockIdx.x * 256 + threadIdx.x;
    int npix = BATCH * RBX * W;
    if (p >= npix) return;
    int b = p / (RBX * W);
    int rem = p - b * (RBX * W);
    int ri = rem / W;
    int col = rem - ri * W;
    int img_row = xbase + ri;
    union { ushort u[8]; uint4 v; } r;
    if (img_row >= 0 && img_row < H) {
        const float* p1 = f1 + (size_t)b * 3 * HW + (size_t)img_row * W + col;
        const float* p3 = f3 + (size_t)b * 3 * HW + (size_t)img_row * W + col;
        r.u[0] = f2h(p1[0]);  r.u[1] = f2h(p1[HW]);  r.u[2] = f2h(p1[2*HW]);
        r.u[3] = f2h(p3[0]);  r.u[4] = f2h(p3[HW]);  r.u[5] = f2h(p3[2*HW]);
        r.u[6] = 0; r.u[7] = 0;
    } else {
        r.v = make_uint4(0, 0, 0, 0);
    }
    *reinterpret_cast<uint4*>(X + (((size_t)b * RBX + ri) * WX + col + 1) * 8) = r.v;
}

// ---------------- pack weights into A-fragment order (f16) ----------------
// A-frag (16x16x32): lane l supplies A[m][k], m = l&15, k = 8*(l>>4)+j, j=0..7
__global__ void pack_w_kernel(const float* __restrict__ w1, const float* __restrict__ w2,
                              const float* __restrict__ w3, const float* __restrict__ w4,
                              ushort* __restrict__ wp1, ushort* __restrict__ wp2,
                              ushort* __restrict__ wp3, ushort* __restrict__ wp4) {
    int i = blockIdx.x * 256 + threadIdx.x;
    if (i < 3072) {
        // wp1: frag f = dy*2+mt ; k -> (dx = k>>3, ci = k&7)
        int j = i & 7, l = (i >> 3) & 63, f = i >> 9;
        int dy = f >> 1, mt = f & 1;
        int dx = l >> 4, ci = j, och = mt * 16 + (l & 15);
        float v = 0.f;
        if (dx < 3 && ci < 6) v = w1[((och * 6 + ci) * 3 + dy) * 3 + dx];
        wp1[i] = f2h(v);
        return;
    }
    i -= 3072;
    if (i < 13824) {
        int j = i & 7, l = (i >> 3) & 63, f = i >> 9;
        int tap = f / 3, mt = f - tap * 3;
        int dy = tap / 3, dx = tap - dy * 3;
        int och = mt * 16 + (l & 15), ci = (l >> 4) * 8 + j;
        wp2[i] = f2h(w2[((och * 32 + ci) * 3 + dy) * 3 + dx]);
        return;
    }
    i -= 13824;
    if (i < 9216) {
        // wp3 first half: ci 0..31
        int j = i & 7, l = (i >> 3) & 63, f = i >> 9;
        int tap = f >> 1, mt = f & 1;
        int dy = tap / 3, dx = tap - dy * 3;
        int och = mt * 16 + (l & 15), ci = (l >> 4) * 8 + j;
        wp3[i] = f2h(w3[((och * 48 + ci) * 3 + dy) * 3 + dx]);
        return;
    }
    i -= 9216;
    if (i < 9216) {
        // wp3 second half: ci 32..63 (zero for ci>=48)
        int j = i & 7, l = (i >> 3) & 63, f = i >> 9;
        int tap = f >> 1, mt = f & 1;
        int dy = tap / 3, dx = tap - dy * 3;
        int och = mt * 16 + (l & 15), ci = 32 + (l >> 4) * 8 + j;
        float v = 0.f;
        if (ci < 48) v = w3[((och * 48 + ci) * 3 + dy) * 3 + dx];
        wp3[9216 + i] = f2h(v);
        return;
    }
    i -= 9216;
    if (i < 4608) {
        int j = i & 7, l = (i >> 3) & 63, tap = i >> 9;
        int dy = tap / 3, dx = tap - dy * 3;
        int och = l & 15, ci = (l >> 4) * 8 + j;
        float v = 0.f;
        if (och < 3) v = w4[((och * 32 + ci) * 3 + dy) * 3 + dx];
        wp4[i] = f2h(v);
    }
}

__device__ __forceinline__ void lds_copy(const unsigned char* __restrict__ g, char* s, int bytes) {
    const uint4* gs = reinterpret_cast<const uint4*>(g);
    uint4* ss = reinterpret_cast<uint4*>(s);
    for (int i = threadIdx.x; i < bytes / 16; i += 256) ss[i] = gs[i];
    __syncthreads();
}

// ---------------- conv1: X(8ch) -> Y1(32ch), relu ----------------
__global__ __launch_bounds__(256) void conv1_kernel(const ushort* __restrict__ Xg,
                                                    const float* __restrict__ bias,
                                                    ushort* __restrict__ Y,
                                                    const unsigned char* __restrict__ wp,
                                                    int y0, int ny, int xbase, int RBX,
                                                    int y1base, int RBY1) {
    __shared__ char lds[6144];
    lds_copy(wp, lds, 6144);
    int wave = threadIdx.x >> 6, lane = threadIdx.x & 63;
    int l15 = lane & 15, lhi = lane >> 4;
    int work = xcd_work(blockIdx.x, gridDim.x);
    int bx = work % 5, t = work / 5, by = t % ny, b = t / ny;
    int y = y0 + by;
    int x0 = bx * 256 + wave * 64;
    bool zrow = (y < 0) | (y >= H);

    f32x4 acc[2][4] = {};
    #pragma unroll
    for (int dy = 0; dy < 3; ++dy) {
        // padded col for lane = x0 + l15 + lhi (dx folded into K via lhi)
        const ushort* rp = Xg + (((size_t)b * RBX + (y + dy - 1 - xbase)) * WX + x0 + l15 + lhi) * 8;
        f16x8 bfrag[4];
        #pragma unroll
        for (int nt = 0; nt < 4; ++nt)
            bfrag[nt] = *reinterpret_cast<const f16x8*>(rp + nt * 128);
        #pragma unroll
        for (int mt = 0; mt < 2; ++mt) {
            f16x8 a = *reinterpret_cast<f16x8*>(lds + ((dy * 2 + mt) * 64 + lane) * 16);
            #pragma unroll
            for (int nt = 0; nt < 4; ++nt)
                acc[mt][nt] = __builtin_amdgcn_mfma_f32_16x16x32_f16(a, bfrag[nt], acc[mt][nt], 0, 0, 0);
        }
    }
    ushort* wpx = Y + (((size_t)b * RBY1 + (y - y1base)) * WP + x0 + l15 + 1) * 32 + lhi * 4;
    #pragma unroll
    for (int mt = 0; mt < 2; ++mt) {
        float4 bs = *reinterpret_cast<const float4*>(bias + mt * 16 + lhi * 4);
        const float* bsp = reinterpret_cast<const float*>(&bs);
        #pragma unroll
        for (int nt = 0; nt < 4; ++nt) {
            ushort o[4];
            #pragma unroll
            for (int r = 0; r < 4; ++r)
                o[r] = zrow ? (ushort)0 : f2h(fmaxf(acc[mt][nt][r] + bsp[r], 0.f));
            *reinterpret_cast<uint2*>(wpx + nt * 512 + mt * 16) = *reinterpret_cast<uint2*>(o);
        }
    }
}

// ---------------- conv2: Y1(32ch) -> Y2(48ch), relu ----------------
__global__ __launch_bounds__(256) void conv2_kernel(const ushort* __restrict__ Y1,
                                                    const float* __restrict__ bias,
                                                    ushort* __restrict__ Y2,
                                                    const unsigned char* __restrict__ wp,
                                                    int y0, int ny, int y1base, int RBY1,
                                                    int y2base, int RBY2) {
    __shared__ char lds[27648];
    lds_copy(wp, lds, 27648);
    int wave = threadIdx.x >> 6, lane = threadIdx.x & 63;
    int l15 = lane & 15, lhi = lane >> 4;
    int work = xcd_work(blockIdx.x, gridDim.x);
    int bx = work % 5, t = work / 5, by = t % ny, b = t / ny;
    int y = y0 + by;
    int x0 = bx * 256 + wave * 64;
    bool zrow = (y < 0) | (y >= H);
    int c0 = x0 + l15;   // padded col of dx=0 tap

    f32x4 acc[3][4] = {};
    #pragma unroll
    for (int dy = 0; dy < 3; ++dy) {
        const ushort* rp = Y1 + (((size_t)b * RBY1 + (y + dy - 1 - y1base)) * WP + c0) * 32 + lhi * 8;
        f16x8 bf[3][4];
        #pragma unroll
        for (int nt = 0; nt < 4; ++nt)
            #pragma unroll
            for (int dx = 0; dx < 3; ++dx)
                bf[dx][nt] = *reinterpret_cast<const f16x8*>(rp + nt * 512 + dx * 32);
        #pragma unroll
        for (int dx = 0; dx < 3; ++dx)
            #pragma unroll
            for (int mt = 0; mt < 3; ++mt) {
                f16x8 a = *reinterpret_cast<f16x8*>(lds + (((dy * 3 + dx) * 3 + mt) * 64 + lane) * 16);
                #pragma unroll
                for (int nt = 0; nt < 4; ++nt)
                    acc[mt][nt] = __builtin_amdgcn_mfma_f32_16x16x32_f16(a, bf[dx][nt], acc[mt][nt], 0, 0, 0);
            }
    }
    ushort* wpx = Y2 + (((size_t)b * RBY2 + (y - y2base)) * WP + x0 + l15 + 1) * 48 + lhi * 4;
    #pragma unroll
    for (int mt = 0; mt < 3; ++mt) {
        float4 bs = *reinterpret_cast<const float4*>(bias + mt * 16 + lhi * 4);
        const float* bsp = reinterpret_cast<const float*>(&bs);
        #pragma unroll
        for (int nt = 0; nt < 4; ++nt) {
            ushort o[4];
            #pragma unroll
            for (int r = 0; r < 4; ++r)
                o[r] = zrow ? (ushort)0 : f2h(fmaxf(acc[mt][nt][r] + bsp[r], 0.f));
            *reinterpret_cast<uint2*>(wpx + nt * 768 + mt * 16) = *reinterpret_cast<uint2*>(o);
        }
    }
}

// ---------------- conv3: Y2(48ch) -> Y3(32ch), relu ----------------
__global__ __launch_bounds__(256) void conv3_kernel(const ushort* __restrict__ Y2,
                                                    const float* __restrict__ bias,
                                                    ushort* __restrict__ Y3,
                                                    const unsigned char* __restrict__ wp,
                                                    int y0, int ny, int y2base, int RBY2,
                                                    int y3base, int RBY3) {
    __shared__ char lds[36864];
    lds_copy(wp, lds, 36864);
    int wave = threadIdx.x >> 6, lane = threadIdx.x & 63;
    int l15 = lane & 15, lhi = lane >> 4;
    int work = xcd_work(blockIdx.x, gridDim.x);
    int bx = work % 5, t = work / 5, by = t % ny, b = t / ny;
    int y = y0 + by;
    int x0 = bx * 256 + wave * 64;
    bool zrow = (y < 0) | (y >= H);
    int c0 = x0 + l15;

    f32x4 acc[2][4] = {};
    #pragma unroll
    for (int dy = 0; dy < 3; ++dy) {
        const ushort* rp = Y2 + (((size_t)b * RBY2 + (y + dy - 1 - y2base)) * WP + c0) * 48 + lhi * 8;
        const ushort* rp2 = rp + 1536;   // nt = 2,3 base (keeps imm offsets < 4 KB)
        // K-half 0 (ci 0..31)
        f16x8 bf[3][4];
        #pragma unroll
        for (int nt = 0; nt < 2; ++nt)
            #pragma unroll
            for (int dx = 0; dx < 3; ++dx) {
                bf[dx][nt]     = *reinterpret_cast<const f16x8*>(rp  + nt * 768 + dx * 48);
                bf[dx][nt + 2] = *reinterpret_cast<const f16x8*>(rp2 + nt * 768 + dx * 48);
            }
        #pragma unroll
        for (int dx = 0; dx < 3; ++dx)
            #pragma unroll
            for (int mt = 0; mt < 2; ++mt) {
                f16x8 a = *reinterpret_cast<f16x8*>(lds + (((dy * 3 + dx) * 2 + mt) * 64 + lane) * 16);
                #pragma unroll
                for (int nt = 0; nt < 4; ++nt)
                    acc[mt][nt] = __builtin_amdgcn_mfma_f32_16x16x32_f16(a, bf[dx][nt], acc[mt][nt], 0, 0, 0);
            }
        // K-half 1 (ci 32..63; weights zero for ci>=48, overreads land in allocated ws)
        #pragma unroll
        for (int nt = 0; nt < 2; ++nt)
            #pragma unroll
            for (int dx = 0; dx < 3; ++dx) {
                bf[dx][nt]     = *reinterpret_cast<const f16x8*>(rp  + nt * 768 + dx * 48 + 32);
                bf[dx][nt + 2] = *reinterpret_cast<const f16x8*>(rp2 + nt * 768 + dx * 48 + 32);
            }
        #pragma unroll
        for (int dx = 0; dx < 3; ++dx)
            #pragma unroll
            for (int mt = 0; mt < 2; ++mt) {
                f16x8 a = *reinterpret_cast<f16x8*>(lds + 18432 + (((dy * 3 + dx) * 2 + mt) * 64 + lane) * 16);
                #pragma unroll
                for (int nt = 0; nt < 4; ++nt)
                    acc[mt][nt] = __builtin_amdgcn_mfma_f32_16x16x32_f16(a, bf[dx][nt], acc[mt][nt], 0, 0, 0);
            }
    }
    ushort* wpx = Y3 + (((size_t)b * RBY3 + (y - y3base)) * WP + x0 + l15 + 1) * 32 + lhi * 4;
    #pragma unroll
    for (int mt = 0; mt < 2; ++mt) {
        float4 bs = *reinterpret_cast<const float4*>(bias + mt * 16 + lhi * 4);
        const float* bsp = reinterpret_cast<const float*>(&bs);
        #pragma unroll
        for (int nt = 0; nt < 4; ++nt) {
            ushort o[4];
            #pragma unroll
            for (int r = 0; r < 4; ++r)
                o[r] = zrow ? (ushort)0 : f2h(fmaxf(acc[mt][nt][r] + bsp[r], 0.f));
            *reinterpret_cast<uint2*>(wpx + nt * 512 + mt * 16) = *reinterpret_cast<uint2*>(o);
        }
    }
}

__device__ __forceinline__ float edgef(float t) {
    float a = 1.f / (1.f + expf(-(t - 0.1f) * 10.f));
    float c = 1.f / (1.f + expf(-(0.9f - t) * 10.f));
    return fminf(a, c);
}

// ---------------- conv4 + mask/avg/clip epilogue -> out NCHW fp32 ----------------
__global__ __launch_bounds__(256) void conv4_kernel(const ushort* __restrict__ Y3,
                                                    const float* __restrict__ b4,
                                                    const float* __restrict__ f1,
                                                    const float* __restrict__ f3,
                                                    float* __restrict__ out,
                                                    const unsigned char* __restrict__ wp,
                                                    int y0, int ny, int y3base, int RBY3) {
    __shared__ char lds[9216];
    lds_copy(wp, lds, 9216);
    int wave = threadIdx.x >> 6, lane = threadIdx.x & 63;
    int l15 = lane & 15, lhi = lane >> 4;
    int work = xcd_work(blockIdx.x, gridDim.x);
    int bx = work % 5, t = work / 5, by = t % ny, b = t / ny;
    int y = y0 + by;
    int x0 = bx * 256 + wave * 64;
    int c0 = x0 + l15;

    f32x4 acc[4] = {};
    #pragma unroll
    for (int dy = 0; dy < 3; ++dy) {
        const ushort* rp = Y3 + (((size_t)b * RBY3 + (y + dy - 1 - y3base)) * WP + c0) * 32 + lhi * 8;
        f16x8 bf[3][4];
        #pragma unroll
        for (int nt = 0; nt < 4; ++nt)
            #pragma unroll
            for (int dx = 0; dx < 3; ++dx)
                bf[dx][nt] = *reinterpret_cast<const f16x8*>(rp + nt * 512 + dx * 32);
        #pragma unroll
        for (int dx = 0; dx < 3; ++dx) {
            f16x8 a = *reinterpret_cast<f16x8*>(lds + ((dy * 3 + dx) * 64 + lane) * 16);
            #pragma unroll
            for (int nt = 0; nt < 4; ++nt)
                acc[nt] = __builtin_amdgcn_mfma_f32_16x16x32_f16(a, bf[dx][nt], acc[nt], 0, 0, 0);
        }
    }
    if (lhi == 0) {   // och = reg index r (0..2) at pixel col l15
        float bv0 = b4[0], bv1 = b4[1], bv2 = b4[2];
        float ty = (float)y * (1.f / (H - 1));
        float ey = edgef(ty);
        #pragma unroll
        for (int nt = 0; nt < 4; ++nt) {
            int x = x0 + nt * 16 + l15;
            float tx = (float)x * (1.f / (W - 1));
            float m = edgef(tx) * ey;
            float om = 1.f - m;
            #pragma unroll
            for (int r = 0; r < 3; ++r) {
                float bv = (r == 0) ? bv0 : (r == 1 ? bv1 : bv2);
                size_t idx = ((size_t)(b * 3 + r) * H + y) * W + x;
                float avg = 0.5f * (f1[idx] + f3[idx]);
                float v = avg * om + (acc[nt][r] + bv) * m;
                out[idx] = fminf(fmaxf(v, -1.f), 1.f);
            }
        }
    }
}

extern "C" void kernel_launch(void* const* d_in, const int* in_sizes, int n_in,
                              void* d_out, int out_size, void* d_ws, size_t ws_size,
                              hipStream_t stream) {
    const float* f1 = (const float*)d_in[0];
    const float* f3 = (const float*)d_in[1];
    const float* w1 = (const float*)d_in[2];
    const float* b1 = (const float*)d_in[3];
    const float* w2 = (const float*)d_in[4];
    const float* b2 = (const float*)d_in[5];
    const float* w3 = (const float*)d_in[6];
    const float* b3 = (const float*)d_in[7];
    const float* w4 = (const float*)d_in[8];
    const float* b4 = (const float*)d_in[9];
    float* out = (float*)d_out;

    // ---- adaptive band sizing (padded layouts) ----
    // bytes = RB*1230848 + 5252096 (+WP reserve 131072)
    int RB = -1;
    for (int nb = 1; nb <= 180; ++nb) {
        int rb = (H + nb - 1) / nb;
        long need = 1230848L * rb + 5252096L + 131072L;
        if (need <= (long)ws_size) { RB = rb; break; }
    }
    if (RB < 0) return;

    int RBX = RB + 8, RBY1 = RB + 6, RBY2 = RB + 4, RBY3 = RB + 2;
    char* ws = (char*)d_ws;
    size_t offX  = 0;
    size_t offY1 = offX  + (size_t)BATCH * RBX  * WX * 8  * 2;
    size_t offY2 = offY1 + (size_t)BATCH * RBY1 * WP * 32 * 2;
    size_t offY3 = offY2 + (size_t)BATCH * RBY2 * WP * 48 * 2;
    size_t offWPr = offY3 + (size_t)BATCH * RBY3 * WP * 32 * 2;
    ushort* X  = (ushort*)(ws + offX);
    ushort* Y1 = (ushort*)(ws + offY1);
    ushort* Y2 = (ushort*)(ws + offY2);
    ushort* Y3 = (ushort*)(ws + offY3);
    ushort* wp1 = (ushort*)(ws + offWPr + WP1_B);
    ushort* wp2 = (ushort*)(ws + offWPr + WP2_B);
    ushort* wp3 = (ushort*)(ws + offWPr + WP3_B);
    ushort* wp4 = (ushort*)(ws + offWPr + WP4_B);

    pack_w_kernel<<<156, 256, 0, stream>>>(w1, w2, w3, w4, wp1, wp2, wp3, wp4);
    int npad = BATCH * (RBX * 4 + (RBY1 + RBY2 + RBY3) * 2);
    zero_pads_kernel<<<(npad + 255) / 256, 256, 0, stream>>>(X, Y1, Y2, Y3, RBX, RBY1, RBY2, RBY3);

    for (int r0 = 0; r0 < H; r0 += RB) {
        int r1 = r0 + RB; if (r1 > H) r1 = H;
        int xbase = r0 - 4, y1base = r0 - 3, y2base = r0 - 2, y3base = r0 - 1;

        int npix = BATCH * RBX * W;
        pack_x_kernel<<<(npix + 255) / 256, 256, 0, stream>>>(f1, f3, X, xbase, RBX);

        int ny1 = (r1 + 3) - (r0 - 3);
        conv1_kernel<<<5 * ny1 * BATCH, 256, 0, stream>>>(
            X, b1, Y1, (const unsigned char*)wp1, r0 - 3, ny1, xbase, RBX, y1base, RBY1);

        int ny2 = (r1 + 2) - (r0 - 2);
        conv2_kernel<<<5 * ny2 * BATCH, 256, 0, stream>>>(
            Y1, b2, Y2, (const unsigned char*)wp2, r0 - 2, ny2, y1base, RBY1, y2base, RBY2);

        int ny3 = (r1 + 1) - (r0 - 1);
        conv3_kernel<<<5 * ny3 * BATCH, 256, 0, stream>>>(
            Y2, b3, Y3, (const unsigned char*)wp3, r0 - 1, ny3, y2base, RBY2, y3base, RBY3);

        int ny4 = r1 - r0;
        conv4_kernel<<<5 * ny4 * BATCH, 256, 0, stream>>>(
            Y3, b4, f1, f3, out, (const unsigned char*)wp4, r0, ny4, y3base, RBY3);
    }
}